// Round 11
// baseline (324.531 us; speedup 1.0000x reference)
//
#include <hip/hip_runtime.h>
#include <math.h>

#define TT 256
#define FF 64
#define HH 20
#define G4 80   // 4*H
#define EPB 4   // batch elems per block (rec)
#define PBLK 320
#define RBLK 640  // 5 waves L1 + 5 waves L2
#define TC 128    // t-chunk per proj block
#define XPAD 72   // xs row stride: 288B, 16B-aligned, 2-way bank conflict max (free)
#define BLOB_BYTES 19456  // 15*80 float4 = 19200, padded

__device__ __forceinline__ float sigmoidf_(float z) {
    return __builtin_amdgcn_rcpf(1.0f + __expf(-z));
}

// quad_perm DPP: value from lane (lane ^ m) within each aligned quad (VALU, no DS)
__device__ __forceinline__ float qpx1(float v) {
    return __int_as_float(__builtin_amdgcn_mov_dpp(__float_as_int(v), 0xB1, 0xF, 0xF, true));
}
__device__ __forceinline__ float qpx2(float v) {
    return __int_as_float(__builtin_amdgcn_mov_dpp(__float_as_int(v), 0x4E, 0xF, 0xF, true));
}
__device__ __forceinline__ float qpx3(float v) {
    return __int_as_float(__builtin_amdgcn_mov_dpp(__float_as_int(v), 0x1B, 0xF, 0xF, true));
}

// ===== K0: lane-ordered blob: blob4[q*80 + j] = {M[(kq*4+k)*80 + col(j)]}
// col(j) = (j&3)*20 + (j>>2) — rec's lane->col mapping baked in, so rec weight
// reloads are lane-contiguous dwordx4 off one base (proven +12 µs in R10).
__global__ void wprep(const float* __restrict__ U1, const float* __restrict__ W2,
                      const float* __restrict__ U2, float4* __restrict__ blob) {
    int i = threadIdx.x + blockIdx.x * blockDim.x;
    if (i >= 15 * G4) return;
    int q = i / G4, j = i - q * G4;
    int m = q / 5, kq = q - m * 5;
    int col = (j & 3) * HH + (j >> 2);
    const float* M = (m == 0) ? U1 : (m == 1) ? W2 : U2;
    float4 v;
    v.x = M[(kq * 4 + 0) * G4 + col];
    v.y = M[(kq * 4 + 1) * G4 + col];
    v.z = M[(kq * 4 + 2) * G4 + col];
    v.w = M[(kq * 4 + 3) * G4 + col];
    blob[i] = v;
}

// ===== K1: xw[t][b][col] = b1[col] + sum_f x[b][t][f]*W1[f][col]
// 8t x 4col register tile; f processed 4-at-a-time with float4 x-reads:
// 12 ds_read_b128 per 128 FMA (was 9 DS per 32 FMA). =====
__global__ __launch_bounds__(PBLK, 2) void proj_x(
    const float* __restrict__ x, const float* __restrict__ W1,
    const float* __restrict__ b1, float* __restrict__ xw, int B)
{
    __shared__ float xs[TC][XPAD];   // 36.9 KB
    __shared__ float ws[FF][G4];     // 20 KB
    __shared__ float bs[G4];
    const int tid = threadIdx.x;
    const int b   = blockIdx.x >> 1;
    const int t0  = (blockIdx.x & 1) * TC;

    const float4* xg = (const float4*)(x + ((size_t)b * TT + t0) * FF);
    for (int i = tid; i < TC * FF / 4; i += PBLK) {
        int t = i >> 4, q = i & 15;
        *(float4*)&xs[t][q * 4] = xg[i];
    }
    const float4* wg = (const float4*)W1;
    float4* wsv = (float4*)ws;
    for (int i = tid; i < FF * G4 / 4; i += PBLK) wsv[i] = wg[i];
    if (tid < G4) bs[tid] = b1[tid];
    __syncthreads();

    const int colq = tid % 20;
    const int tq   = tid / 20;    // 0..15
    const int c0   = colq * 4;
    const int tb   = tq * 8;      // 8 rows per thread

    const float4 bias4 = *(const float4*)&bs[c0];
    float4 acc[8];
#pragma unroll
    for (int i = 0; i < 8; ++i) acc[i] = bias4;

#pragma unroll 4
    for (int q = 0; q < FF / 4; ++q) {
        float4 wv0 = *(const float4*)&ws[4*q+0][c0];
        float4 wv1 = *(const float4*)&ws[4*q+1][c0];
        float4 wv2 = *(const float4*)&ws[4*q+2][c0];
        float4 wv3 = *(const float4*)&ws[4*q+3][c0];
#pragma unroll
        for (int r = 0; r < 8; ++r) {
            float4 xr = *(const float4*)&xs[tb + r][q * 4];
            acc[r].x = fmaf(xr.x, wv0.x, acc[r].x);
            acc[r].y = fmaf(xr.x, wv0.y, acc[r].y);
            acc[r].z = fmaf(xr.x, wv0.z, acc[r].z);
            acc[r].w = fmaf(xr.x, wv0.w, acc[r].w);
            acc[r].x = fmaf(xr.y, wv1.x, acc[r].x);
            acc[r].y = fmaf(xr.y, wv1.y, acc[r].y);
            acc[r].z = fmaf(xr.y, wv1.z, acc[r].z);
            acc[r].w = fmaf(xr.y, wv1.w, acc[r].w);
            acc[r].x = fmaf(xr.z, wv2.x, acc[r].x);
            acc[r].y = fmaf(xr.z, wv2.y, acc[r].y);
            acc[r].z = fmaf(xr.z, wv2.z, acc[r].z);
            acc[r].w = fmaf(xr.z, wv2.w, acc[r].w);
            acc[r].x = fmaf(xr.w, wv3.x, acc[r].x);
            acc[r].y = fmaf(xr.w, wv3.y, acc[r].y);
            acc[r].z = fmaf(xr.w, wv3.z, acc[r].z);
            acc[r].w = fmaf(xr.w, wv3.w, acc[r].w);
        }
    }
#pragma unroll
    for (int i = 0; i < 8; ++i) {
        *(float4*)&xw[((size_t)(t0 + tb + i) * B + b) * G4 + c0] = acc[i];
    }
}

// ============ K2: producer-consumer recurrence — UNCHANGED from R10 (173 µs) ============
__global__ __launch_bounds__(RBLK, 2) void lstm2_pc(
    const float* __restrict__ xw, const float4* __restrict__ blob,
    const float* __restrict__ b2,
    const float* __restrict__ Wd, const float* __restrict__ bd,
    float* __restrict__ out, int B)
{
    const int tid  = threadIdx.x;
    const bool isL1 = tid < 320;
    const int rt   = isL1 ? tid : tid - 320;
    const int elem = rt / G4;          // 0..3
    const int j    = rt - elem * G4;   // 0..79
    const int g    = j & 3;            // gate: 0=i 1=f 2=c 3=o
    const int u    = j >> 2;           // unit 0..19
    const int col  = g * HH + u;
    const int b0   = blockIdx.x * EPB;

    __shared__ float h1b[2][EPB][24];
    __shared__ float h2b[2][EPB][24];

    const float4* wb4 = blob + j;
    float wA[HH], wB[HH];
    if (isL1) {
#pragma unroll
        for (int q = 0; q < 5; ++q) {
            float4 v = wb4[q * G4];
            wA[4*q+0] = v.x; wA[4*q+1] = v.y; wA[4*q+2] = v.z; wA[4*q+3] = v.w;
        }
    } else {
#pragma unroll
        for (int q = 0; q < 5; ++q) {
            float4 v = wb4[(5 + q) * G4];
            wA[4*q+0] = v.x; wA[4*q+1] = v.y; wA[4*q+2] = v.z; wA[4*q+3] = v.w;
            float4 v2 = wb4[(10 + q) * G4];
            wB[4*q+0] = v2.x; wB[4*q+1] = v2.y; wB[4*q+2] = v2.z; wB[4*q+3] = v2.w;
        }
    }
    const float bias = isL1 ? 0.f : b2[col];

    for (int i = tid; i < 2 * EPB * 24; i += RBLK) ((float*)h1b)[i] = 0.f;
    for (int i = tid; i < 2 * EPB * 24; i += RBLK) ((float*)h2b)[i] = 0.f;

    const size_t tstride = (size_t)B * G4;
    const float* xwp = xw + (size_t)(b0 + elem) * G4 + col;
    float xwc = isL1 ? xwp[0] : 0.f;
    xwp += tstride;
    float c1 = 0.f, c2 = 0.f;
    __syncthreads();

    for (int i = 0; i <= TT; ++i) {
        const int rb = (i + 1) & 1;    // read buffers
        const int wb = i & 1;          // write buffers

        if (isL1 && i < TT) {
            float xwn = 0.f;
            if (i + 1 < TT) xwn = *xwp;
            xwp += tstride;

            float zz0 = 0.f, zz1 = 0.f, zz2 = 0.f, zz3 = 0.f;
            const float4* hv = (const float4*)h1b[rb][elem];
#pragma unroll
            for (int q = 0; q < HH / 4; ++q) {
                float4 hh = hv[q];
                zz0 = fmaf(hh.x, wA[4*q+0], zz0);
                zz1 = fmaf(hh.y, wA[4*q+1], zz1);
                zz2 = fmaf(hh.z, wA[4*q+2], zz2);
                zz3 = fmaf(hh.w, wA[4*q+3], zz3);
            }
            float z = xwc + ((zz0 + zz1) + (zz2 + zz3));

            float a = (g == 2) ? fmaxf(z, 0.f) : sigmoidf_(z);
            float a1 = qpx1(a), a2 = qpx2(a), a3 = qpx3(a);
            c1 = a1 * c1 + a * a2;
            float h1n = a3 * fmaxf(c1, 0.f);
            if (g == 0) h1b[wb][elem][u] = h1n;
            xwc = xwn;
        }
        if (!isL1 && i >= 1) {
            float y0 = 0.f, y1 = 0.f, y2 = 0.f, y3 = 0.f;
            const float4* h1v = (const float4*)h1b[rb][elem];
            const float4* h2v = (const float4*)h2b[rb][elem];
#pragma unroll
            for (int q = 0; q < HH / 4; ++q) {
                float4 ha = h1v[q];
                float4 hb = h2v[q];
                y0 = fmaf(ha.x, wA[4*q+0], y0);
                y1 = fmaf(ha.y, wA[4*q+1], y1);
                y2 = fmaf(ha.z, wA[4*q+2], y2);
                y3 = fmaf(ha.w, wA[4*q+3], y3);
                y0 = fmaf(hb.x, wB[4*q+0], y0);
                y1 = fmaf(hb.y, wB[4*q+1], y1);
                y2 = fmaf(hb.z, wB[4*q+2], y2);
                y3 = fmaf(hb.w, wB[4*q+3], y3);
            }
            float z2v = bias + ((y0 + y1) + (y2 + y3));

            float bgt = (g == 2) ? fmaxf(z2v, 0.f) : sigmoidf_(z2v);
            float b1_ = qpx1(bgt), b2_ = qpx2(bgt), b3_ = qpx3(bgt);
            c2 = b1_ * c2 + bgt * b2_;
            float h2n = b3_ * fmaxf(c2, 0.f);
            if (g == 0) h2b[wb][elem][u] = h2n;
        }
        __syncthreads();
    }

    if (tid < EPB) {
        float acc = bd[0];
#pragma unroll
        for (int k = 0; k < HH; ++k) acc += h2b[0][tid][k] * Wd[k];
        out[b0 + tid] = acc;
    }
}

// ================= Fallback (ws too small): fused single kernel =================
__global__ __launch_bounds__(PBLK, 2) void lstm2_fused_fb(
    const float* __restrict__ x,
    const float* __restrict__ W1, const float* __restrict__ U1, const float* __restrict__ b1,
    const float* __restrict__ W2, const float* __restrict__ U2, const float* __restrict__ b2,
    const float* __restrict__ Wd, const float* __restrict__ bd,
    float* __restrict__ out)
{
    const int tid  = threadIdx.x;
    const int elem = tid / G4;
    const int j    = tid - elem * G4;
    const int g    = j & 3;
    const int u    = j >> 2;
    const int col  = g * HH + u;
    const int b0   = blockIdx.x * EPB;

    __shared__ float xs[2][EPB][FF];
    __shared__ float h1b[2][EPB][24];
    __shared__ float h2b[2][EPB][24];

    float w1[FF], u1[HH], w2[HH], u2[HH];
#pragma unroll
    for (int f = 0; f < FF; ++f) w1[f] = W1[f * G4 + col];
#pragma unroll
    for (int k = 0; k < HH; ++k) u1[k] = U1[k * G4 + col];
#pragma unroll
    for (int k = 0; k < HH; ++k) w2[k] = W2[k * G4 + col];
#pragma unroll
    for (int k = 0; k < HH; ++k) u2[k] = U2[k * G4 + col];
    const float bias1 = b1[col];
    const float bias2 = b2[col];

    for (int i = tid; i < 2 * EPB * 24; i += PBLK) ((float*)h1b)[i] = 0.f;
    for (int i = tid; i < 2 * EPB * 24; i += PBLK) ((float*)h2b)[i] = 0.f;
    if (tid < EPB * FF) {
        int e2 = tid >> 6, f2 = tid & 63;
        xs[0][e2][f2] = x[((long)(b0 + e2) * TT + 0) * FF + f2];
    }
    __syncthreads();

    float c1 = 0.f, c2 = 0.f;
    for (int t = 0; t < TT; ++t) {
        const int cur = t & 1;
        float xpre = 0.f;
        if (t + 1 < TT && tid < EPB * FF) {
            int e2 = tid >> 6, f2 = tid & 63;
            xpre = x[((long)(b0 + e2) * TT + (t + 1)) * FF + f2];
        }
        float zz0 = 0.f, zz1 = 0.f, zz2 = 0.f, zz3 = 0.f;
        const float4* xv = (const float4*)xs[cur][elem];
#pragma unroll
        for (int q = 0; q < FF / 4; ++q) {
            float4 xx = xv[q];
            zz0 = fmaf(xx.x, w1[4*q+0], zz0);
            zz1 = fmaf(xx.y, w1[4*q+1], zz1);
            zz2 = fmaf(xx.z, w1[4*q+2], zz2);
            zz3 = fmaf(xx.w, w1[4*q+3], zz3);
        }
        const float4* hv = (const float4*)h1b[cur][elem];
#pragma unroll
        for (int q = 0; q < HH / 4; ++q) {
            float4 hh = hv[q];
            zz0 = fmaf(hh.x, u1[4*q+0], zz0);
            zz1 = fmaf(hh.y, u1[4*q+1], zz1);
            zz2 = fmaf(hh.z, u1[4*q+2], zz2);
            zz3 = fmaf(hh.w, u1[4*q+3], zz3);
        }
        float z = bias1 + ((zz0 + zz1) + (zz2 + zz3));
        float a = (g == 2) ? fmaxf(z, 0.f) : sigmoidf_(z);
        float a1 = qpx1(a), a2 = qpx2(a), a3 = qpx3(a);
        c1 = a1 * c1 + a * a2;
        float h1n = a3 * fmaxf(c1, 0.f);
        if (g == 0) h1b[cur ^ 1][elem][u] = h1n;
        __syncthreads();
        if (t + 1 < TT && tid < EPB * FF) xs[cur ^ 1][tid >> 6][tid & 63] = xpre;

        float y0 = 0.f, y1 = 0.f, y2 = 0.f, y3 = 0.f;
        const float4* h1v = (const float4*)h1b[cur ^ 1][elem];
        const float4* h2v = (const float4*)h2b[cur][elem];
#pragma unroll
        for (int q = 0; q < HH / 4; ++q) {
            float4 ha = h1v[q];
            float4 hb = h2v[q];
            y0 = fmaf(ha.x, w2[4*q+0], y0);
            y1 = fmaf(ha.y, w2[4*q+1], y1);
            y2 = fmaf(ha.z, w2[4*q+2], y2);
            y3 = fmaf(ha.w, w2[4*q+3], y3);
            y0 = fmaf(hb.x, u2[4*q+0], y0);
            y1 = fmaf(hb.y, u2[4*q+1], y1);
            y2 = fmaf(hb.z, u2[4*q+2], y2);
            y3 = fmaf(hb.w, u2[4*q+3], y3);
        }
        float z2v = bias2 + ((y0 + y1) + (y2 + y3));
        float bgt = (g == 2) ? fmaxf(z2v, 0.f) : sigmoidf_(z2v);
        float b1_ = qpx1(bgt), b2_ = qpx2(bgt), b3_ = qpx3(bgt);
        c2 = b1_ * c2 + bgt * b2_;
        float h2n = b3_ * fmaxf(c2, 0.f);
        if (g == 0) h2b[cur ^ 1][elem][u] = h2n;
        __syncthreads();
    }
    if (j == 0) {
        float acc = bd[0];
#pragma unroll
        for (int k = 0; k < HH; ++k) acc += h2b[0][elem][k] * Wd[k];
        out[b0 + elem] = acc;
    }
}

extern "C" void kernel_launch(void* const* d_in, const int* in_sizes, int n_in,
                              void* d_out, int out_size, void* d_ws, size_t ws_size,
                              hipStream_t stream) {
    const float* x  = (const float*)d_in[0];
    const float* W1 = (const float*)d_in[1];
    const float* U1 = (const float*)d_in[2];
    const float* b1 = (const float*)d_in[3];
    const float* W2 = (const float*)d_in[4];
    const float* U2 = (const float*)d_in[5];
    const float* b2 = (const float*)d_in[6];
    const float* Wd = (const float*)d_in[7];
    const float* bd = (const float*)d_in[8];
    float* out = (float*)d_out;
    const int B = in_sizes[0] / (TT * FF);   // 2048

    const size_t need = (size_t)BLOB_BYTES + (size_t)B * TT * G4 * sizeof(float);
    if (ws_size >= need) {
        float4* blob = (float4*)d_ws;
        float*  xw   = (float*)((char*)d_ws + BLOB_BYTES);
        hipLaunchKernelGGL(wprep, dim3(5), dim3(256), 0, stream, U1, W2, U2, blob);
        hipLaunchKernelGGL(proj_x, dim3(B * (TT / TC)), dim3(PBLK), 0, stream,
                           x, W1, b1, xw, B);
        hipLaunchKernelGGL(lstm2_pc, dim3(B / EPB), dim3(RBLK), 0, stream,
                           xw, blob, b2, Wd, bd, out, B);
    } else {
        hipLaunchKernelGGL(lstm2_fused_fb, dim3(B / EPB), dim3(PBLK), 0, stream,
                           x, W1, U1, b1, W2, U2, b2, Wd, bd, out);
    }
}

// Round 12
// 295.396 us; speedup vs baseline: 1.0986x; 1.0986x over previous
//
#include <hip/hip_runtime.h>
#include <math.h>

#define TT 256
#define FF 64
#define HH 20
#define G4 80   // 4*H
#define EPB 4   // batch elems per block (rec)
#define PBLK 320
#define RBLK 640  // 5 waves L1 + 5 waves L2
#define PTC 128   // t-chunk per proj block
#define BLOB_BYTES 19456  // 15*80 float4 = 19200, padded

__device__ __forceinline__ float sigmoidf_(float z) {
    return __builtin_amdgcn_rcpf(1.0f + __expf(-z));
}

// quad_perm DPP: value from lane (lane ^ m) within each aligned quad (VALU, no DS)
__device__ __forceinline__ float qpx1(float v) {
    return __int_as_float(__builtin_amdgcn_mov_dpp(__float_as_int(v), 0xB1, 0xF, 0xF, true));
}
__device__ __forceinline__ float qpx2(float v) {
    return __int_as_float(__builtin_amdgcn_mov_dpp(__float_as_int(v), 0x4E, 0xF, 0xF, true));
}
__device__ __forceinline__ float qpx3(float v) {
    return __int_as_float(__builtin_amdgcn_mov_dpp(__float_as_int(v), 0x1B, 0xF, 0xF, true));
}

// ===== K0: lane-ordered blob: blob4[q*80 + j] = {M[(kq*4+k)*80 + col(j)]}
// col(j) = (j&3)*20 + (j>>2) — rec's lane->col mapping baked in (R10: +12 µs win).
__global__ void wprep(const float* __restrict__ U1, const float* __restrict__ W2,
                      const float* __restrict__ U2, float4* __restrict__ blob) {
    int i = threadIdx.x + blockIdx.x * blockDim.x;
    if (i >= 15 * G4) return;
    int q = i / G4, j = i - q * G4;
    int m = q / 5, kq = q - m * 5;
    int col = (j & 3) * HH + (j >> 2);
    const float* M = (m == 0) ? U1 : (m == 1) ? W2 : U2;
    float4 v;
    v.x = M[(kq * 4 + 0) * G4 + col];
    v.y = M[(kq * 4 + 1) * G4 + col];
    v.z = M[(kq * 4 + 2) * G4 + col];
    v.w = M[(kq * 4 + 3) * G4 + col];
    blob[i] = v;
}

// ===== K1: xw[t][b][col] = b1[col] + sum_f x[b][t][f]*W1[f][col]
// Rotation-swizzled x tile: (t,f) stored at xs[t][(f + 4*(t>>3)) & 63].
// A wave's 4 row-groups get rotations {0,4,8,12} dwords -> disjoint bank
// windows -> conflict-free ds_read_b128 (R11's pad gave 4-way, 13.6M conflicts).
__global__ __launch_bounds__(PBLK, 2) void proj_x(
    const float* __restrict__ x, const float* __restrict__ W1,
    const float* __restrict__ b1, float* __restrict__ xw, int B)
{
    __shared__ float xs[PTC][FF];    // 32 KB, rotated
    __shared__ float ws[FF][G4];     // 20 KB
    __shared__ float bs[G4];
    const int tid = threadIdx.x;
    const int b   = blockIdx.x >> 1;
    const int t0  = (blockIdx.x & 1) * PTC;

    // stage x with rotation baked into the write
    const float4* xg = (const float4*)(x + ((size_t)b * TT + t0) * FF);
    for (int i = tid; i < PTC * 16; i += PBLK) {
        int t = i >> 4, q = i & 15;
        int c = (4 * q + 4 * ((t >> 3) & 15)) & 63;
        *(float4*)&xs[t][c] = xg[i];
    }
    const float4* wg = (const float4*)W1;
    float4* wsv = (float4*)ws;
    for (int i = tid; i < FF * G4 / 4; i += PBLK) wsv[i] = wg[i];
    if (tid < G4) bs[tid] = b1[tid];
    __syncthreads();

    const int cq  = tid % 20;     // col group: 4 cols
    const int tq  = tid / 20;     // row group: 8 rows, 0..15
    const int c0  = cq * 4;
    const int tb  = tq * 8;
    const int rot = 4 * tq;       // per-lane-constant read rotation (dwords)

    const float4 bias4 = *(const float4*)&bs[c0];
    float4 acc[8];
#pragma unroll
    for (int r = 0; r < 8; ++r) acc[r] = bias4;

#pragma unroll 4
    for (int q = 0; q < 16; ++q) {
        const int xc = (4 * q + rot) & 63;
        float4 wv0 = *(const float4*)&ws[4*q+0][c0];
        float4 wv1 = *(const float4*)&ws[4*q+1][c0];
        float4 wv2 = *(const float4*)&ws[4*q+2][c0];
        float4 wv3 = *(const float4*)&ws[4*q+3][c0];
#pragma unroll
        for (int r = 0; r < 8; ++r) {
            float4 xr = *(const float4*)&xs[tb + r][xc];
            acc[r].x = fmaf(xr.x, wv0.x, acc[r].x);
            acc[r].y = fmaf(xr.x, wv0.y, acc[r].y);
            acc[r].z = fmaf(xr.x, wv0.z, acc[r].z);
            acc[r].w = fmaf(xr.x, wv0.w, acc[r].w);
            acc[r].x = fmaf(xr.y, wv1.x, acc[r].x);
            acc[r].y = fmaf(xr.y, wv1.y, acc[r].y);
            acc[r].z = fmaf(xr.y, wv1.z, acc[r].z);
            acc[r].w = fmaf(xr.y, wv1.w, acc[r].w);
            acc[r].x = fmaf(xr.z, wv2.x, acc[r].x);
            acc[r].y = fmaf(xr.z, wv2.y, acc[r].y);
            acc[r].z = fmaf(xr.z, wv2.z, acc[r].z);
            acc[r].w = fmaf(xr.z, wv2.w, acc[r].w);
            acc[r].x = fmaf(xr.w, wv3.x, acc[r].x);
            acc[r].y = fmaf(xr.w, wv3.y, acc[r].y);
            acc[r].z = fmaf(xr.w, wv3.z, acc[r].z);
            acc[r].w = fmaf(xr.w, wv3.w, acc[r].w);
        }
    }
#pragma unroll
    for (int r = 0; r < 8; ++r) {
        *(float4*)&xw[((size_t)(t0 + tb + r) * B + b) * G4 + c0] = acc[r];
    }
}

// ============ K2: producer-consumer recurrence — UNCHANGED from R10 (173 µs) ============
__global__ __launch_bounds__(RBLK, 2) void lstm2_pc(
    const float* __restrict__ xw, const float4* __restrict__ blob,
    const float* __restrict__ b2,
    const float* __restrict__ Wd, const float* __restrict__ bd,
    float* __restrict__ out, int B)
{
    const int tid  = threadIdx.x;
    const bool isL1 = tid < 320;
    const int rt   = isL1 ? tid : tid - 320;
    const int elem = rt / G4;          // 0..3
    const int j    = rt - elem * G4;   // 0..79
    const int g    = j & 3;            // gate: 0=i 1=f 2=c 3=o
    const int u    = j >> 2;           // unit 0..19
    const int col  = g * HH + u;
    const int b0   = blockIdx.x * EPB;

    __shared__ float h1b[2][EPB][24];
    __shared__ float h2b[2][EPB][24];

    const float4* wb4 = blob + j;
    float wA[HH], wB[HH];
    if (isL1) {
#pragma unroll
        for (int q = 0; q < 5; ++q) {
            float4 v = wb4[q * G4];
            wA[4*q+0] = v.x; wA[4*q+1] = v.y; wA[4*q+2] = v.z; wA[4*q+3] = v.w;
        }
    } else {
#pragma unroll
        for (int q = 0; q < 5; ++q) {
            float4 v = wb4[(5 + q) * G4];
            wA[4*q+0] = v.x; wA[4*q+1] = v.y; wA[4*q+2] = v.z; wA[4*q+3] = v.w;
            float4 v2 = wb4[(10 + q) * G4];
            wB[4*q+0] = v2.x; wB[4*q+1] = v2.y; wB[4*q+2] = v2.z; wB[4*q+3] = v2.w;
        }
    }
    const float bias = isL1 ? 0.f : b2[col];

    for (int i = tid; i < 2 * EPB * 24; i += RBLK) ((float*)h1b)[i] = 0.f;
    for (int i = tid; i < 2 * EPB * 24; i += RBLK) ((float*)h2b)[i] = 0.f;

    const size_t tstride = (size_t)B * G4;
    const float* xwp = xw + (size_t)(b0 + elem) * G4 + col;
    float xwc = isL1 ? xwp[0] : 0.f;
    xwp += tstride;
    float c1 = 0.f, c2 = 0.f;
    __syncthreads();

    for (int i = 0; i <= TT; ++i) {
        const int rb = (i + 1) & 1;    // read buffers
        const int wb = i & 1;          // write buffers

        if (isL1 && i < TT) {
            float xwn = 0.f;
            if (i + 1 < TT) xwn = *xwp;
            xwp += tstride;

            float zz0 = 0.f, zz1 = 0.f, zz2 = 0.f, zz3 = 0.f;
            const float4* hv = (const float4*)h1b[rb][elem];
#pragma unroll
            for (int q = 0; q < HH / 4; ++q) {
                float4 hh = hv[q];
                zz0 = fmaf(hh.x, wA[4*q+0], zz0);
                zz1 = fmaf(hh.y, wA[4*q+1], zz1);
                zz2 = fmaf(hh.z, wA[4*q+2], zz2);
                zz3 = fmaf(hh.w, wA[4*q+3], zz3);
            }
            float z = xwc + ((zz0 + zz1) + (zz2 + zz3));

            float a = (g == 2) ? fmaxf(z, 0.f) : sigmoidf_(z);
            float a1 = qpx1(a), a2 = qpx2(a), a3 = qpx3(a);
            c1 = a1 * c1 + a * a2;
            float h1n = a3 * fmaxf(c1, 0.f);
            if (g == 0) h1b[wb][elem][u] = h1n;
            xwc = xwn;
        }
        if (!isL1 && i >= 1) {
            float y0 = 0.f, y1 = 0.f, y2 = 0.f, y3 = 0.f;
            const float4* h1v = (const float4*)h1b[rb][elem];
            const float4* h2v = (const float4*)h2b[rb][elem];
#pragma unroll
            for (int q = 0; q < HH / 4; ++q) {
                float4 ha = h1v[q];
                float4 hb = h2v[q];
                y0 = fmaf(ha.x, wA[4*q+0], y0);
                y1 = fmaf(ha.y, wA[4*q+1], y1);
                y2 = fmaf(ha.z, wA[4*q+2], y2);
                y3 = fmaf(ha.w, wA[4*q+3], y3);
                y0 = fmaf(hb.x, wB[4*q+0], y0);
                y1 = fmaf(hb.y, wB[4*q+1], y1);
                y2 = fmaf(hb.z, wB[4*q+2], y2);
                y3 = fmaf(hb.w, wB[4*q+3], y3);
            }
            float z2v = bias + ((y0 + y1) + (y2 + y3));

            float bgt = (g == 2) ? fmaxf(z2v, 0.f) : sigmoidf_(z2v);
            float b1_ = qpx1(bgt), b2_ = qpx2(bgt), b3_ = qpx3(bgt);
            c2 = b1_ * c2 + bgt * b2_;
            float h2n = b3_ * fmaxf(c2, 0.f);
            if (g == 0) h2b[wb][elem][u] = h2n;
        }
        __syncthreads();
    }

    if (tid < EPB) {
        float acc = bd[0];
#pragma unroll
        for (int k = 0; k < HH; ++k) acc += h2b[0][tid][k] * Wd[k];
        out[b0 + tid] = acc;
    }
}

// ================= Fallback (ws too small): fused single kernel =================
__global__ __launch_bounds__(PBLK, 2) void lstm2_fused_fb(
    const float* __restrict__ x,
    const float* __restrict__ W1, const float* __restrict__ U1, const float* __restrict__ b1,
    const float* __restrict__ W2, const float* __restrict__ U2, const float* __restrict__ b2,
    const float* __restrict__ Wd, const float* __restrict__ bd,
    float* __restrict__ out)
{
    const int tid  = threadIdx.x;
    const int elem = tid / G4;
    const int j    = tid - elem * G4;
    const int g    = j & 3;
    const int u    = j >> 2;
    const int col  = g * HH + u;
    const int b0   = blockIdx.x * EPB;

    __shared__ float xs[2][EPB][FF];
    __shared__ float h1b[2][EPB][24];
    __shared__ float h2b[2][EPB][24];

    float w1[FF], u1[HH], w2[HH], u2[HH];
#pragma unroll
    for (int f = 0; f < FF; ++f) w1[f] = W1[f * G4 + col];
#pragma unroll
    for (int k = 0; k < HH; ++k) u1[k] = U1[k * G4 + col];
#pragma unroll
    for (int k = 0; k < HH; ++k) w2[k] = W2[k * G4 + col];
#pragma unroll
    for (int k = 0; k < HH; ++k) u2[k] = U2[k * G4 + col];
    const float bias1 = b1[col];
    const float bias2 = b2[col];

    for (int i = tid; i < 2 * EPB * 24; i += PBLK) ((float*)h1b)[i] = 0.f;
    for (int i = tid; i < 2 * EPB * 24; i += PBLK) ((float*)h2b)[i] = 0.f;
    if (tid < EPB * FF) {
        int e2 = tid >> 6, f2 = tid & 63;
        xs[0][e2][f2] = x[((long)(b0 + e2) * TT + 0) * FF + f2];
    }
    __syncthreads();

    float c1 = 0.f, c2 = 0.f;
    for (int t = 0; t < TT; ++t) {
        const int cur = t & 1;
        float xpre = 0.f;
        if (t + 1 < TT && tid < EPB * FF) {
            int e2 = tid >> 6, f2 = tid & 63;
            xpre = x[((long)(b0 + e2) * TT + (t + 1)) * FF + f2];
        }
        float zz0 = 0.f, zz1 = 0.f, zz2 = 0.f, zz3 = 0.f;
        const float4* xv = (const float4*)xs[cur][elem];
#pragma unroll
        for (int q = 0; q < FF / 4; ++q) {
            float4 xx = xv[q];
            zz0 = fmaf(xx.x, w1[4*q+0], zz0);
            zz1 = fmaf(xx.y, w1[4*q+1], zz1);
            zz2 = fmaf(xx.z, w1[4*q+2], zz2);
            zz3 = fmaf(xx.w, w1[4*q+3], zz3);
        }
        const float4* hv = (const float4*)h1b[cur][elem];
#pragma unroll
        for (int q = 0; q < HH / 4; ++q) {
            float4 hh = hv[q];
            zz0 = fmaf(hh.x, u1[4*q+0], zz0);
            zz1 = fmaf(hh.y, u1[4*q+1], zz1);
            zz2 = fmaf(hh.z, u1[4*q+2], zz2);
            zz3 = fmaf(hh.w, u1[4*q+3], zz3);
        }
        float z = bias1 + ((zz0 + zz1) + (zz2 + zz3));
        float a = (g == 2) ? fmaxf(z, 0.f) : sigmoidf_(z);
        float a1 = qpx1(a), a2 = qpx2(a), a3 = qpx3(a);
        c1 = a1 * c1 + a * a2;
        float h1n = a3 * fmaxf(c1, 0.f);
        if (g == 0) h1b[cur ^ 1][elem][u] = h1n;
        __syncthreads();
        if (t + 1 < TT && tid < EPB * FF) xs[cur ^ 1][tid >> 6][tid & 63] = xpre;

        float y0 = 0.f, y1 = 0.f, y2 = 0.f, y3 = 0.f;
        const float4* h1v = (const float4*)h1b[cur ^ 1][elem];
        const float4* h2v = (const float4*)h2b[cur][elem];
#pragma unroll
        for (int q = 0; q < HH / 4; ++q) {
            float4 ha = h1v[q];
            float4 hb = h2v[q];
            y0 = fmaf(ha.x, w2[4*q+0], y0);
            y1 = fmaf(ha.y, w2[4*q+1], y1);
            y2 = fmaf(ha.z, w2[4*q+2], y2);
            y3 = fmaf(ha.w, w2[4*q+3], y3);
            y0 = fmaf(hb.x, u2[4*q+0], y0);
            y1 = fmaf(hb.y, u2[4*q+1], y1);
            y2 = fmaf(hb.z, u2[4*q+2], y2);
            y3 = fmaf(hb.w, u2[4*q+3], y3);
        }
        float z2v = bias2 + ((y0 + y1) + (y2 + y3));
        float bgt = (g == 2) ? fmaxf(z2v, 0.f) : sigmoidf_(z2v);
        float b1_ = qpx1(bgt), b2_ = qpx2(bgt), b3_ = qpx3(bgt);
        c2 = b1_ * c2 + bgt * b2_;
        float h2n = b3_ * fmaxf(c2, 0.f);
        if (g == 0) h2b[cur ^ 1][elem][u] = h2n;
        __syncthreads();
    }
    if (j == 0) {
        float acc = bd[0];
#pragma unroll
        for (int k = 0; k < HH; ++k) acc += h2b[0][elem][k] * Wd[k];
        out[b0 + elem] = acc;
    }
}

extern "C" void kernel_launch(void* const* d_in, const int* in_sizes, int n_in,
                              void* d_out, int out_size, void* d_ws, size_t ws_size,
                              hipStream_t stream) {
    const float* x  = (const float*)d_in[0];
    const float* W1 = (const float*)d_in[1];
    const float* U1 = (const float*)d_in[2];
    const float* b1 = (const float*)d_in[3];
    const float* W2 = (const float*)d_in[4];
    const float* U2 = (const float*)d_in[5];
    const float* b2 = (const float*)d_in[6];
    const float* Wd = (const float*)d_in[7];
    const float* bd = (const float*)d_in[8];
    float* out = (float*)d_out;
    const int B = in_sizes[0] / (TT * FF);   // 2048

    const size_t need = (size_t)BLOB_BYTES + (size_t)B * TT * G4 * sizeof(float);
    if (ws_size >= need) {
        float4* blob = (float4*)d_ws;
        float*  xw   = (float*)((char*)d_ws + BLOB_BYTES);
        hipLaunchKernelGGL(wprep, dim3(5), dim3(256), 0, stream, U1, W2, U2, blob);
        hipLaunchKernelGGL(proj_x, dim3(B * (TT / PTC)), dim3(PBLK), 0, stream,
                           x, W1, b1, xw, B);
        hipLaunchKernelGGL(lstm2_pc, dim3(B / EPB), dim3(RBLK), 0, stream,
                           xw, blob, b2, Wd, bd, out, B);
    } else {
        hipLaunchKernelGGL(lstm2_fused_fb, dim3(B / EPB), dim3(PBLK), 0, stream,
                           x, W1, U1, b1, W2, U2, b2, Wd, bd, out);
    }
}

// Round 13
// 214.952 us; speedup vs baseline: 1.5098x; 1.3742x over previous
//
#include <hip/hip_runtime.h>
#include <math.h>

#define TT 256
#define FF 64
#define HH 20
#define G4 80   // 4*H
#define EPB 4   // batch elems per block (rec)
#define PBLK 320
#define RBLK 640  // 5 waves L1 + 5 waves L2
#define BLOB_BYTES 19456   // 15*80 float4
#define WTHI_OFF 19456     // 80*64 ushort = 10240
#define WTLO_OFF 29696
#define XW_OFF   40960

typedef __attribute__((ext_vector_type(8))) short short8x;
typedef __attribute__((ext_vector_type(4))) float f32x4;

__device__ __forceinline__ float sigmoidf_(float z) {
    return __builtin_amdgcn_rcpf(1.0f + __expf(-z));
}
__device__ __forceinline__ float qpx1(float v) {
    return __int_as_float(__builtin_amdgcn_mov_dpp(__float_as_int(v), 0xB1, 0xF, 0xF, true));
}
__device__ __forceinline__ float qpx2(float v) {
    return __int_as_float(__builtin_amdgcn_mov_dpp(__float_as_int(v), 0x4E, 0xF, 0xF, true));
}
__device__ __forceinline__ float qpx3(float v) {
    return __int_as_float(__builtin_amdgcn_mov_dpp(__float_as_int(v), 0x1B, 0xF, 0xF, true));
}
__device__ __forceinline__ unsigned short bft(float f) {   // truncate to bf16
    return (unsigned short)(__float_as_uint(f) >> 16);
}

// ===== K0: (a) rec blob (R10-proven); (b) W1 -> transposed bf16 hi/lo =====
__global__ void wprep(const float* __restrict__ U1, const float* __restrict__ W2,
                      const float* __restrict__ U2, const float* __restrict__ W1,
                      float4* __restrict__ blob,
                      unsigned short* __restrict__ wthi, unsigned short* __restrict__ wtlo) {
    int i = threadIdx.x + blockIdx.x * blockDim.x;
    if (i < 15 * G4) {
        int q = i / G4, j = i - q * G4;
        int m = q / 5, kq = q - m * 5;
        int col = (j & 3) * HH + (j >> 2);
        const float* M = (m == 0) ? U1 : (m == 1) ? W2 : U2;
        float4 v;
        v.x = M[(kq * 4 + 0) * G4 + col];
        v.y = M[(kq * 4 + 1) * G4 + col];
        v.z = M[(kq * 4 + 2) * G4 + col];
        v.w = M[(kq * 4 + 3) * G4 + col];
        blob[i] = v;
    } else if (i < 15 * G4 + FF * G4) {
        int idx = i - 15 * G4;
        int col = idx / FF, f = idx - col * FF;    // wt[col][f]
        float w = W1[f * G4 + col];
        unsigned short h = bft(w);
        float fh = __uint_as_float((unsigned)h << 16);
        wthi[col * FF + f] = h;
        wtlo[col * FF + f] = bft(w - fh);
    }
}

// ===== K1: split-bf16 MFMA proj: xw[t][b][col] = b1 + x@W1 =====
// block = 256 thr (4 waves), tile M=128 rows (one b, half the t-range), N=80, K=64.
// wave tile: 32 rows x 80 cols = 2 mt x 5 nt C-tiles of 16x16, K as 2 slabs of 32.
// 3-term split: Ah*Bh + Al*Bh + Ah*Bl (fp32 acc) -> ~1e-4 rel accuracy.
// Frag maps: A[i][k] i=lane&15, k=(lane>>4)*8+e; B[k][j] j=lane&15, same k;
// C col=lane&15, row=(lane>>4)*4+reg (m89-verified).
__global__ __launch_bounds__(256, 4) void proj_mfma(
    const float* __restrict__ x,
    const unsigned short* __restrict__ wthi, const unsigned short* __restrict__ wtlo,
    const float* __restrict__ b1, float* __restrict__ xw, int B)
{
    __shared__ unsigned short Bthi[G4][72];   // 72-pad: 144B rows -> 2-way max (free)
    __shared__ unsigned short Btlo[G4][72];
    const int tid = threadIdx.x;
    const int l   = tid & 63;
    const int w   = tid >> 6;          // wave 0..3
    const int b   = blockIdx.x >> 1;
    const int t0  = (blockIdx.x & 1) * 128;
    const int lane16 = l & 15;
    const int lgrp   = l >> 4;

    // stage W hi/lo into LDS (16B chunks)
    for (int c = tid; c < G4 * FF / 8; c += 256) {
        int row = c >> 3, cc = (c & 7) * 8;
        *(short8x*)&Bthi[row][cc] = *(const short8x*)&wthi[row * FF + cc];
        *(short8x*)&Btlo[row][cc] = *(const short8x*)&wtlo[row * FF + cc];
    }
    __syncthreads();

    float bias[5];
#pragma unroll
    for (int nt = 0; nt < 5; ++nt) bias[nt] = b1[nt * 16 + lane16];

    f32x4 acc[2][5];
#pragma unroll
    for (int mt = 0; mt < 2; ++mt)
#pragma unroll
        for (int nt = 0; nt < 5; ++nt) acc[mt][nt] = (f32x4){0.f, 0.f, 0.f, 0.f};

#pragma unroll
    for (int mt = 0; mt < 2; ++mt) {
        // A fragments (hi/lo) for this mt, both k-slabs, direct from global x
        short8x Ah[2], Al[2];
        const int trow = t0 + w * 32 + mt * 16 + lane16;
        const float* xr = x + ((size_t)b * TT + trow) * FF + lgrp * 8;
#pragma unroll
        for (int ks = 0; ks < 2; ++ks) {
            float4 va = *(const float4*)(xr + ks * 32);
            float4 vb = *(const float4*)(xr + ks * 32 + 4);
            float v[8] = {va.x, va.y, va.z, va.w, vb.x, vb.y, vb.z, vb.w};
#pragma unroll
            for (int e = 0; e < 8; ++e) {
                unsigned short h = bft(v[e]);
                float fh = __uint_as_float((unsigned)h << 16);
                Ah[ks][e] = (short)h;
                Al[ks][e] = (short)bft(v[e] - fh);
            }
        }
#pragma unroll
        for (int nt = 0; nt < 5; ++nt) {
#pragma unroll
            for (int ks = 0; ks < 2; ++ks) {
                short8x bh = *(const short8x*)&Bthi[nt * 16 + lane16][ks * 32 + lgrp * 8];
                short8x bl = *(const short8x*)&Btlo[nt * 16 + lane16][ks * 32 + lgrp * 8];
                acc[mt][nt] = __builtin_amdgcn_mfma_f32_16x16x32_bf16(Ah[ks], bh, acc[mt][nt], 0, 0, 0);
                acc[mt][nt] = __builtin_amdgcn_mfma_f32_16x16x32_bf16(Al[ks], bh, acc[mt][nt], 0, 0, 0);
                acc[mt][nt] = __builtin_amdgcn_mfma_f32_16x16x32_bf16(Ah[ks], bl, acc[mt][nt], 0, 0, 0);
            }
        }
    }

    // store: C row -> t, col -> xw col; xw[t][b][col]
#pragma unroll
    for (int mt = 0; mt < 2; ++mt) {
        const int trb = t0 + w * 32 + mt * 16 + lgrp * 4;
#pragma unroll
        for (int nt = 0; nt < 5; ++nt) {
            const int col = nt * 16 + lane16;
#pragma unroll
            for (int r = 0; r < 4; ++r) {
                xw[((size_t)(trb + r) * B + b) * G4 + col] = acc[mt][nt][r] + bias[nt];
            }
        }
    }
}

// ============ K2: producer-consumer recurrence — UNCHANGED from R10 (173 µs) ============
__global__ __launch_bounds__(RBLK, 2) void lstm2_pc(
    const float* __restrict__ xw, const float4* __restrict__ blob,
    const float* __restrict__ b2,
    const float* __restrict__ Wd, const float* __restrict__ bd,
    float* __restrict__ out, int B)
{
    const int tid  = threadIdx.x;
    const bool isL1 = tid < 320;
    const int rt   = isL1 ? tid : tid - 320;
    const int elem = rt / G4;          // 0..3
    const int j    = rt - elem * G4;   // 0..79
    const int g    = j & 3;            // gate: 0=i 1=f 2=c 3=o
    const int u    = j >> 2;           // unit 0..19
    const int col  = g * HH + u;
    const int b0   = blockIdx.x * EPB;

    __shared__ float h1b[2][EPB][24];
    __shared__ float h2b[2][EPB][24];

    const float4* wb4 = blob + j;
    float wA[HH], wB[HH];
    if (isL1) {
#pragma unroll
        for (int q = 0; q < 5; ++q) {
            float4 v = wb4[q * G4];
            wA[4*q+0] = v.x; wA[4*q+1] = v.y; wA[4*q+2] = v.z; wA[4*q+3] = v.w;
        }
    } else {
#pragma unroll
        for (int q = 0; q < 5; ++q) {
            float4 v = wb4[(5 + q) * G4];
            wA[4*q+0] = v.x; wA[4*q+1] = v.y; wA[4*q+2] = v.z; wA[4*q+3] = v.w;
            float4 v2 = wb4[(10 + q) * G4];
            wB[4*q+0] = v2.x; wB[4*q+1] = v2.y; wB[4*q+2] = v2.z; wB[4*q+3] = v2.w;
        }
    }
    const float bias = isL1 ? 0.f : b2[col];

    for (int i = tid; i < 2 * EPB * 24; i += RBLK) ((float*)h1b)[i] = 0.f;
    for (int i = tid; i < 2 * EPB * 24; i += RBLK) ((float*)h2b)[i] = 0.f;

    const size_t tstride = (size_t)B * G4;
    const float* xwp = xw + (size_t)(b0 + elem) * G4 + col;
    float xwc = isL1 ? xwp[0] : 0.f;
    xwp += tstride;
    float c1 = 0.f, c2 = 0.f;
    __syncthreads();

    for (int i = 0; i <= TT; ++i) {
        const int rb = (i + 1) & 1;    // read buffers
        const int wb = i & 1;          // write buffers

        if (isL1 && i < TT) {
            float xwn = 0.f;
            if (i + 1 < TT) xwn = *xwp;
            xwp += tstride;

            float zz0 = 0.f, zz1 = 0.f, zz2 = 0.f, zz3 = 0.f;
            const float4* hv = (const float4*)h1b[rb][elem];
#pragma unroll
            for (int q = 0; q < HH / 4; ++q) {
                float4 hh = hv[q];
                zz0 = fmaf(hh.x, wA[4*q+0], zz0);
                zz1 = fmaf(hh.y, wA[4*q+1], zz1);
                zz2 = fmaf(hh.z, wA[4*q+2], zz2);
                zz3 = fmaf(hh.w, wA[4*q+3], zz3);
            }
            float z = xwc + ((zz0 + zz1) + (zz2 + zz3));

            float a = (g == 2) ? fmaxf(z, 0.f) : sigmoidf_(z);
            float a1 = qpx1(a), a2 = qpx2(a), a3 = qpx3(a);
            c1 = a1 * c1 + a * a2;
            float h1n = a3 * fmaxf(c1, 0.f);
            if (g == 0) h1b[wb][elem][u] = h1n;
            xwc = xwn;
        }
        if (!isL1 && i >= 1) {
            float y0 = 0.f, y1 = 0.f, y2 = 0.f, y3 = 0.f;
            const float4* h1v = (const float4*)h1b[rb][elem];
            const float4* h2v = (const float4*)h2b[rb][elem];
#pragma unroll
            for (int q = 0; q < HH / 4; ++q) {
                float4 ha = h1v[q];
                float4 hb = h2v[q];
                y0 = fmaf(ha.x, wA[4*q+0], y0);
                y1 = fmaf(ha.y, wA[4*q+1], y1);
                y2 = fmaf(ha.z, wA[4*q+2], y2);
                y3 = fmaf(ha.w, wA[4*q+3], y3);
                y0 = fmaf(hb.x, wB[4*q+0], y0);
                y1 = fmaf(hb.y, wB[4*q+1], y1);
                y2 = fmaf(hb.z, wB[4*q+2], y2);
                y3 = fmaf(hb.w, wB[4*q+3], y3);
            }
            float z2v = bias + ((y0 + y1) + (y2 + y3));

            float bgt = (g == 2) ? fmaxf(z2v, 0.f) : sigmoidf_(z2v);
            float b1_ = qpx1(bgt), b2_ = qpx2(bgt), b3_ = qpx3(bgt);
            c2 = b1_ * c2 + bgt * b2_;
            float h2n = b3_ * fmaxf(c2, 0.f);
            if (g == 0) h2b[wb][elem][u] = h2n;
        }
        __syncthreads();
    }

    if (tid < EPB) {
        float acc = bd[0];
#pragma unroll
        for (int k = 0; k < HH; ++k) acc += h2b[0][tid][k] * Wd[k];
        out[b0 + tid] = acc;
    }
}

// ================= Fallback (ws too small): fused single kernel =================
__global__ __launch_bounds__(PBLK, 2) void lstm2_fused_fb(
    const float* __restrict__ x,
    const float* __restrict__ W1, const float* __restrict__ U1, const float* __restrict__ b1,
    const float* __restrict__ W2, const float* __restrict__ U2, const float* __restrict__ b2,
    const float* __restrict__ Wd, const float* __restrict__ bd,
    float* __restrict__ out)
{
    const int tid  = threadIdx.x;
    const int elem = tid / G4;
    const int j    = tid - elem * G4;
    const int g    = j & 3;
    const int u    = j >> 2;
    const int col  = g * HH + u;
    const int b0   = blockIdx.x * EPB;

    __shared__ float xs[2][EPB][FF];
    __shared__ float h1b[2][EPB][24];
    __shared__ float h2b[2][EPB][24];

    float w1[FF], u1[HH], w2[HH], u2[HH];
#pragma unroll
    for (int f = 0; f < FF; ++f) w1[f] = W1[f * G4 + col];
#pragma unroll
    for (int k = 0; k < HH; ++k) u1[k] = U1[k * G4 + col];
#pragma unroll
    for (int k = 0; k < HH; ++k) w2[k] = W2[k * G4 + col];
#pragma unroll
    for (int k = 0; k < HH; ++k) u2[k] = U2[k * G4 + col];
    const float bias1 = b1[col];
    const float bias2 = b2[col];

    for (int i = tid; i < 2 * EPB * 24; i += PBLK) ((float*)h1b)[i] = 0.f;
    for (int i = tid; i < 2 * EPB * 24; i += PBLK) ((float*)h2b)[i] = 0.f;
    if (tid < EPB * FF) {
        int e2 = tid >> 6, f2 = tid & 63;
        xs[0][e2][f2] = x[((long)(b0 + e2) * TT + 0) * FF + f2];
    }
    __syncthreads();

    float c1 = 0.f, c2 = 0.f;
    for (int t = 0; t < TT; ++t) {
        const int cur = t & 1;
        float xpre = 0.f;
        if (t + 1 < TT && tid < EPB * FF) {
            int e2 = tid >> 6, f2 = tid & 63;
            xpre = x[((long)(b0 + e2) * TT + (t + 1)) * FF + f2];
        }
        float zz0 = 0.f, zz1 = 0.f, zz2 = 0.f, zz3 = 0.f;
        const float4* xv = (const float4*)xs[cur][elem];
#pragma unroll
        for (int q = 0; q < FF / 4; ++q) {
            float4 xx = xv[q];
            zz0 = fmaf(xx.x, w1[4*q+0], zz0);
            zz1 = fmaf(xx.y, w1[4*q+1], zz1);
            zz2 = fmaf(xx.z, w1[4*q+2], zz2);
            zz3 = fmaf(xx.w, w1[4*q+3], zz3);
        }
        const float4* hv = (const float4*)h1b[cur][elem];
#pragma unroll
        for (int q = 0; q < HH / 4; ++q) {
            float4 hh = hv[q];
            zz0 = fmaf(hh.x, u1[4*q+0], zz0);
            zz1 = fmaf(hh.y, u1[4*q+1], zz1);
            zz2 = fmaf(hh.z, u1[4*q+2], zz2);
            zz3 = fmaf(hh.w, u1[4*q+3], zz3);
        }
        float z = bias1 + ((zz0 + zz1) + (zz2 + zz3));
        float a = (g == 2) ? fmaxf(z, 0.f) : sigmoidf_(z);
        float a1 = qpx1(a), a2 = qpx2(a), a3 = qpx3(a);
        c1 = a1 * c1 + a * a2;
        float h1n = a3 * fmaxf(c1, 0.f);
        if (g == 0) h1b[cur ^ 1][elem][u] = h1n;
        __syncthreads();
        if (t + 1 < TT && tid < EPB * FF) xs[cur ^ 1][tid >> 6][tid & 63] = xpre;

        float y0 = 0.f, y1 = 0.f, y2 = 0.f, y3 = 0.f;
        const float4* h1v = (const float4*)h1b[cur ^ 1][elem];
        const float4* h2v = (const float4*)h2b[cur][elem];
#pragma unroll
        for (int q = 0; q < HH / 4; ++q) {
            float4 ha = h1v[q];
            float4 hb = h2v[q];
            y0 = fmaf(ha.x, w2[4*q+0], y0);
            y1 = fmaf(ha.y, w2[4*q+1], y1);
            y2 = fmaf(ha.z, w2[4*q+2], y2);
            y3 = fmaf(ha.w, w2[4*q+3], y3);
            y0 = fmaf(hb.x, u2[4*q+0], y0);
            y1 = fmaf(hb.y, u2[4*q+1], y1);
            y2 = fmaf(hb.z, u2[4*q+2], y2);
            y3 = fmaf(hb.w, u2[4*q+3], y3);
        }
        float z2v = bias2 + ((y0 + y1) + (y2 + y3));
        float bgt = (g == 2) ? fmaxf(z2v, 0.f) : sigmoidf_(z2v);
        float b1_ = qpx1(bgt), b2_ = qpx2(bgt), b3_ = qpx3(bgt);
        c2 = b1_ * c2 + bgt * b2_;
        float h2n = b3_ * fmaxf(c2, 0.f);
        if (g == 0) h2b[cur ^ 1][elem][u] = h2n;
        __syncthreads();
    }
    if (j == 0) {
        float acc = bd[0];
#pragma unroll
        for (int k = 0; k < HH; ++k) acc += h2b[0][elem][k] * Wd[k];
        out[b0 + elem] = acc;
    }
}

extern "C" void kernel_launch(void* const* d_in, const int* in_sizes, int n_in,
                              void* d_out, int out_size, void* d_ws, size_t ws_size,
                              hipStream_t stream) {
    const float* x  = (const float*)d_in[0];
    const float* W1 = (const float*)d_in[1];
    const float* U1 = (const float*)d_in[2];
    const float* b1 = (const float*)d_in[3];
    const float* W2 = (const float*)d_in[4];
    const float* U2 = (const float*)d_in[5];
    const float* b2 = (const float*)d_in[6];
    const float* Wd = (const float*)d_in[7];
    const float* bd = (const float*)d_in[8];
    float* out = (float*)d_out;
    const int B = in_sizes[0] / (TT * FF);   // 2048

    const size_t need = (size_t)XW_OFF + (size_t)B * TT * G4 * sizeof(float);
    if (ws_size >= need) {
        float4* blob = (float4*)d_ws;
        unsigned short* wthi = (unsigned short*)((char*)d_ws + WTHI_OFF);
        unsigned short* wtlo = (unsigned short*)((char*)d_ws + WTLO_OFF);
        float* xw = (float*)((char*)d_ws + XW_OFF);
        hipLaunchKernelGGL(wprep, dim3(26), dim3(256), 0, stream,
                           U1, W2, U2, W1, blob, wthi, wtlo);
        hipLaunchKernelGGL(proj_mfma, dim3(B * 2), dim3(256), 0, stream,
                           x, wthi, wtlo, b1, xw, B);
        hipLaunchKernelGGL(lstm2_pc, dim3(B / EPB), dim3(RBLK), 0, stream,
                           xw, blob, b2, Wd, bd, out, B);
    } else {
        hipLaunchKernelGGL(lstm2_fused_fb, dim3(B / EPB), dim3(PBLK), 0, stream,
                           x, W1, U1, b1, W2, U2, b2, Wd, bd, out);
    }
}